// Round 1
// baseline (18008.626 us; speedup 1.0000x reference)
//
#include <hip/hip_runtime.h>
#include <math.h>

#define D_ACT   2048
#define N_FEAT  32768
#define K_SPARSE 64
#define BATCH   8192

#define BM 128
#define BN 128
#define BK 16

// ---------------------------------------------------------------------------
// Kernel 1: inv_norm[row] = 1 / (||dict_w[row]|| + 1e-6), fp64 accumulation.
// ---------------------------------------------------------------------------
__global__ __launch_bounds__(256) void norm_kernel(const float* __restrict__ w,
                                                   float* __restrict__ inv_norm) {
  const int row = blockIdx.x;
  const int t = threadIdx.x;
  const float4* w4 = (const float4*)(w + (size_t)row * D_ACT);
  double s = 0.0;
#pragma unroll
  for (int i = 0; i < 2; ++i) {
    float4 v = w4[t + i * 256];
    s += (double)v.x * v.x + (double)v.y * v.y + (double)v.z * v.z + (double)v.w * v.w;
  }
  __shared__ double red[256];
  red[t] = s;
  __syncthreads();
  for (int off = 128; off > 0; off >>= 1) {
    if (t < off) red[t] += red[t + off];
    __syncthreads();
  }
  if (t == 0) inv_norm[row] = (float)(1.0 / (sqrt(red[0]) + 1e-6));
}

// ---------------------------------------------------------------------------
// Kernel 2: scores = (x @ W^T) * inv_norm[n], written to d_out as scratch.
// fp32 VALU GEMM, 128x128 tile, 8x8 per thread, two-level accumulation
// (flush every 64 K) to keep accumulation error ~1.5e-7.
// ---------------------------------------------------------------------------
__global__ __launch_bounds__(256, 2) void sgemm_kernel(
    const float* __restrict__ X, const float* __restrict__ W,
    const float* __restrict__ inv_norm, float* __restrict__ out) {
  __shared__ float As[BK][BM];
  __shared__ float Bs[BK][BN];
  const int t  = threadIdx.x;
  const int tx = t & 15;
  const int ty = t >> 4;
  const int m0 = blockIdx.y * BM;
  const int n0 = blockIdx.x * BN;

  // staging: 2 threads per tile-row, each loads 8 contiguous floats (2x float4)
  const int r  = t >> 1;
  const int kq = (t & 1) * 8;
  const float* xrow = X + (size_t)(m0 + r) * D_ACT + kq;
  const float* wrow = W + (size_t)(n0 + r) * D_ACT + kq;

  float acc[8][8], accT[8][8];
#pragma unroll
  for (int i = 0; i < 8; ++i)
#pragma unroll
    for (int j = 0; j < 8; ++j) { acc[i][j] = 0.f; accT[i][j] = 0.f; }

  for (int kt = 0; kt < D_ACT / BK; ++kt) {
    const int k0 = kt * BK;
    float4 fa0 = *(const float4*)(xrow + k0);
    float4 fa1 = *(const float4*)(xrow + k0 + 4);
    float4 fb0 = *(const float4*)(wrow + k0);
    float4 fb1 = *(const float4*)(wrow + k0 + 4);
    __syncthreads();  // previous iteration's compute done before overwrite
    As[kq + 0][r] = fa0.x; As[kq + 1][r] = fa0.y; As[kq + 2][r] = fa0.z; As[kq + 3][r] = fa0.w;
    As[kq + 4][r] = fa1.x; As[kq + 5][r] = fa1.y; As[kq + 6][r] = fa1.z; As[kq + 7][r] = fa1.w;
    Bs[kq + 0][r] = fb0.x; Bs[kq + 1][r] = fb0.y; Bs[kq + 2][r] = fb0.z; Bs[kq + 3][r] = fb0.w;
    Bs[kq + 4][r] = fb1.x; Bs[kq + 5][r] = fb1.y; Bs[kq + 6][r] = fb1.z; Bs[kq + 7][r] = fb1.w;
    __syncthreads();
#pragma unroll
    for (int kk = 0; kk < BK; ++kk) {
      float a[8], b[8];
      *(float4*)&a[0] = *(const float4*)&As[kk][ty * 8];
      *(float4*)&a[4] = *(const float4*)&As[kk][ty * 8 + 4];
      *(float4*)&b[0] = *(const float4*)&Bs[kk][tx * 8];
      *(float4*)&b[4] = *(const float4*)&Bs[kk][tx * 8 + 4];
#pragma unroll
      for (int i = 0; i < 8; ++i)
#pragma unroll
        for (int j = 0; j < 8; ++j)
          accT[i][j] = fmaf(a[i], b[j], accT[i][j]);
    }
    if ((kt & 3) == 3) {  // flush every 64 K: two-level accumulation
#pragma unroll
      for (int i = 0; i < 8; ++i)
#pragma unroll
        for (int j = 0; j < 8; ++j) { acc[i][j] += accT[i][j]; accT[i][j] = 0.f; }
    }
  }

  float inv[8];
#pragma unroll
  for (int j = 0; j < 8; ++j) inv[j] = inv_norm[n0 + tx * 8 + j];

#pragma unroll
  for (int i = 0; i < 8; ++i) {
    float vals[8];
#pragma unroll
    for (int j = 0; j < 8; ++j) vals[j] = acc[i][j] * inv[j];
    float* orow = out + (size_t)(m0 + ty * 8 + i) * N_FEAT + n0 + tx * 8;
    *(float4*)(orow)     = *(float4*)&vals[0];
    *(float4*)(orow + 4) = *(float4*)&vals[4];
  }
}

// ---------------------------------------------------------------------------
// Kernel 3: per-row exact top-64 in-place rewrite of d_out.
// Monotone key: ascending uint order == ascending float order.
// 4096-bin histogram on top 12 key bits -> threshold bin -> exact stable
// (value desc, index asc) ranking of the in-bin candidates.
// ---------------------------------------------------------------------------
#define NBIN 4096
#define MAXC 1024

__device__ __forceinline__ unsigned int fkey(float f) {
  unsigned int b = __float_as_uint(f);
  return (b & 0x80000000u) ? ~b : (b | 0x80000000u);
}

__global__ __launch_bounds__(256) void topk_kernel(float* __restrict__ scores) {
  const int row = blockIdx.x;
  float* srow = scores + (size_t)row * N_FEAT;
  const int t = threadIdx.x;

  __shared__ unsigned int hist[NBIN];
  __shared__ unsigned int csum[256];
  __shared__ float cval[MAXC];
  __shared__ int   cidx[MAXC];
  __shared__ unsigned char selc[MAXC];
  __shared__ unsigned int ccount;
  __shared__ int binT;
  __shared__ int aboveT;

  for (int i = t; i < NBIN; i += 256) hist[i] = 0;
  if (t == 0) ccount = 0;
  __syncthreads();

  // pass 1: histogram
  for (int i = t; i < N_FEAT; i += 256)
    atomicAdd(&hist[fkey(srow[i]) >> 20], 1u);
  __syncthreads();

  // suffix scan (coarse per-thread chunk, then serial in thread 0)
  unsigned int cs = 0;
#pragma unroll
  for (int i = 0; i < 16; ++i) cs += hist[t * 16 + i];
  csum[t] = cs;
  __syncthreads();

  if (t == 0) {
    unsigned int cum = 0;
    int c = 255;
    for (; c > 0; --c) {
      if (cum + csum[c] >= (unsigned)K_SPARSE) break;
      cum += csum[c];
    }
    int b = c * 16 + 15;
    while (cum + hist[b] < (unsigned)K_SPARSE) { cum += hist[b]; --b; }
    binT = b;
    aboveT = (int)cum;  // count of elements strictly in higher bins (< 64)
  }
  __syncthreads();

  // pass 2: collect candidates in the threshold bin
  const int bT = binT;
  for (int i = t; i < N_FEAT; i += 256) {
    float v = srow[i];
    if ((int)(fkey(v) >> 20) == bT) {
      unsigned int p = atomicAdd(&ccount, 1u);
      if (p < MAXC) { cval[p] = v; cidx[p] = i; }
    }
  }
  __syncthreads();

  const int C = (ccount < (unsigned)MAXC) ? (int)ccount : MAXC;
  const int need = K_SPARSE - aboveT;  // >= 1 by construction
  for (int i = t; i < C; i += 256) {
    const unsigned int ui = fkey(cval[i]);
    const int ii = cidx[i];
    int rank = 0;
    for (int j = 0; j < C; ++j) {
      const unsigned int uj = fkey(cval[j]);
      rank += (uj > ui) || (uj == ui && cidx[j] < ii);
    }
    selc[i] = (rank < need) ? 1 : 0;
  }
  __syncthreads();

  // pass 3: rewrite row — keep (relu) everything in higher bins, zero the rest
  for (int i = t; i < N_FEAT; i += 256) {
    float v = srow[i];
    srow[i] = ((int)(fkey(v) >> 20) > bT) ? fmaxf(v, 0.0f) : 0.0f;
  }
  __syncthreads();
  // fix up selected candidates from the threshold bin
  for (int i = t; i < C; i += 256)
    if (selc[i]) srow[cidx[i]] = fmaxf(cval[i], 0.0f);
}

// ---------------------------------------------------------------------------
extern "C" void kernel_launch(void* const* d_in, const int* in_sizes, int n_in,
                              void* d_out, int out_size, void* d_ws, size_t ws_size,
                              hipStream_t stream) {
  const float* x = (const float*)d_in[0];   // [BATCH, D_ACT]
  const float* w = (const float*)d_in[1];   // [N_FEAT, D_ACT]
  float* out = (float*)d_out;               // [BATCH, N_FEAT]
  float* inv_norm = (float*)d_ws;           // 32768 floats = 128 KiB

  norm_kernel<<<dim3(N_FEAT), dim3(256), 0, stream>>>(w, inv_norm);
  sgemm_kernel<<<dim3(N_FEAT / BN, BATCH / BM), dim3(256), 0, stream>>>(x, w, inv_norm, out);
  topk_kernel<<<dim3(BATCH), dim3(256), 0, stream>>>(out);
}

// Round 3
// 3041.568 us; speedup vs baseline: 5.9208x; 5.9208x over previous
//
#include <hip/hip_runtime.h>
#include <math.h>

#define D_ACT    2048
#define N_FEAT   32768
#define K_SPARSE 64
#define BATCH    8192

// bf16 operand region lives in the upper 64KB of each 128KB output slot.
// logical operand byte j -> d_out byte 65536 + (j & 65535) + ((j>>16)<<17)
#define XB_BYTES 33554432u   // BATCH*D_ACT*2
#define MB_BINS  1
#define MAXC     1024
#define HWORDS   4096        // 8192 u16 bins packed in 4096 u32 words

typedef __attribute__((ext_vector_type(8))) short short8;
typedef __attribute__((ext_vector_type(4))) float f32x4;
typedef __attribute__((ext_vector_type(8))) unsigned short us8;

__device__ __forceinline__ unsigned obyte(unsigned j) {
  return 65536u + (j & 65535u) + ((j >> 16) << 17);
}

__device__ __forceinline__ unsigned short f2bf(float f) {
  unsigned u = __float_as_uint(f);
  return (unsigned short)((u + 0x7FFFu + ((u >> 16) & 1u)) >> 16);
}

// bf16 bits -> monotone 16-bit key
__device__ __forceinline__ unsigned bfkey(unsigned h) {
  return (h & 0x8000u) ? (~h & 0xFFFFu) : (h | 0x8000u);
}

// ---------------------------------------------------------------------------
// inv_norm in fp64 (exact-ish); fp32 copy for the bf16 W conversion.
// ---------------------------------------------------------------------------
__global__ __launch_bounds__(256) void norm_kernel(const float* __restrict__ w,
                                                   float* __restrict__ invf,
                                                   double* __restrict__ invd) {
  const int row = blockIdx.x, t = threadIdx.x;
  const float4* w4 = (const float4*)(w + (size_t)row * D_ACT);
  double s = 0.0;
#pragma unroll
  for (int i = 0; i < 2; ++i) {
    float4 v = w4[t + i * 256];
    s += (double)v.x * v.x + (double)v.y * v.y + (double)v.z * v.z + (double)v.w * v.w;
  }
  __shared__ double red[256];
  red[t] = s; __syncthreads();
  for (int off = 128; off > 0; off >>= 1) { if (t < off) red[t] += red[t + off]; __syncthreads(); }
  if (t == 0) { double inv = 1.0 / (sqrt(red[0]) + 1e-6); invd[row] = inv; invf[row] = (float)inv; }
}

// ---------------------------------------------------------------------------
// fp32 -> bf16 converters, writing into the slot-interleaved operand region.
// ---------------------------------------------------------------------------
__global__ __launch_bounds__(256) void cvt_x_kernel(const float* __restrict__ x,
                                                    char* __restrict__ ob) {
  const int NT = BATCH * D_ACT / 4;
  for (int i = blockIdx.x * 256 + threadIdx.x; i < NT; i += gridDim.x * 256) {
    float4 v = ((const float4*)x)[i];
    ushort4 o; o.x = f2bf(v.x); o.y = f2bf(v.y); o.z = f2bf(v.z); o.w = f2bf(v.w);
    *(ushort4*)(ob + obyte((unsigned)i * 8u)) = o;
  }
}

__global__ __launch_bounds__(256) void cvt_w_kernel(const float* __restrict__ w,
                                                    const float* __restrict__ invf,
                                                    char* __restrict__ ob) {
  const int NT = N_FEAT * D_ACT / 4;
  for (int i = blockIdx.x * 256 + threadIdx.x; i < NT; i += gridDim.x * 256) {
    float4 v = ((const float4*)w)[i];
    float inv = invf[i >> 9];
    ushort4 o; o.x = f2bf(v.x * inv); o.y = f2bf(v.y * inv); o.z = f2bf(v.z * inv); o.w = f2bf(v.w * inv);
    *(ushort4*)(ob + obyte(XB_BYTES + (unsigned)i * 8u)) = o;
  }
}

// ---------------------------------------------------------------------------
// bf16 MFMA GEMM: scores = xb @ wb^T, 128x128 tile, BK=64, 4 waves (2x2).
// global_load_lds w16 with XOR-swizzled SOURCE addresses (LDS stays linear);
// ds_read applies the same XOR -> conflict-free b128 fragment reads.
// Scores written bf16 into each row's own slot lower half.
// ---------------------------------------------------------------------------
__global__ __launch_bounds__(256) void gemm_bf16_kernel(const char* __restrict__ ob,
                                                        unsigned short* __restrict__ sc) {
  __shared__ char As[16384];
  __shared__ char Bs[16384];
  const int t = threadIdx.x;
  const int lane = t & 63, wid = t >> 6;
  const int wr = wid >> 1, wc = wid & 1;
  const int m0 = blockIdx.y * 128, n0 = blockIdx.x * 128;

  f32x4 acc[4][4];
#pragma unroll
  for (int i = 0; i < 4; ++i)
#pragma unroll
    for (int j = 0; j < 4; ++j)
#pragma unroll
      for (int q = 0; q < 4; ++q) acc[i][j][q] = 0.f;

  for (int kt = 0; kt < D_ACT / 64; ++kt) {
    const unsigned kb = (unsigned)kt * 128u;
#pragma unroll
    for (int i = 0; i < 4; ++i) {
      const int idx = i * 256 + t;
      const int row = idx >> 3, ch = idx & 7;
      const int sch = ch ^ (row & 7);
      const unsigned jA = (unsigned)(m0 + row) * 4096u + kb + (unsigned)sch * 16u;
      const unsigned jB = XB_BYTES + (unsigned)(n0 + row) * 4096u + kb + (unsigned)sch * 16u;
      __builtin_amdgcn_global_load_lds(
          (const __attribute__((address_space(1))) unsigned int*)(ob + obyte(jA)),
          (__attribute__((address_space(3))) unsigned int*)(As + idx * 16), 16, 0, 0);
      __builtin_amdgcn_global_load_lds(
          (const __attribute__((address_space(1))) unsigned int*)(ob + obyte(jB)),
          (__attribute__((address_space(3))) unsigned int*)(Bs + idx * 16), 16, 0, 0);
    }
    __syncthreads();
#pragma unroll
    for (int kc = 0; kc < 2; ++kc) {
      short8 a[4], b[4];
#pragma unroll
      for (int mt = 0; mt < 4; ++mt) {
        const int row = wr * 64 + mt * 16 + (lane & 15);
        const int c = kc * 4 + (lane >> 4);
        a[mt] = *(const short8*)(As + row * 128 + (c ^ (row & 7)) * 16);
      }
#pragma unroll
      for (int nt = 0; nt < 4; ++nt) {
        const int row = wc * 64 + nt * 16 + (lane & 15);
        const int c = kc * 4 + (lane >> 4);
        b[nt] = *(const short8*)(Bs + row * 128 + (c ^ (row & 7)) * 16);
      }
#pragma unroll
      for (int mt = 0; mt < 4; ++mt)
#pragma unroll
        for (int nt = 0; nt < 4; ++nt)
          acc[mt][nt] = __builtin_amdgcn_mfma_f32_16x16x32_bf16(a[mt], b[nt], acc[mt][nt], 0, 0, 0);
    }
    __syncthreads();
  }

  // epilogue: bf16 scores at ushort index m*65536 + n (slot-interleaved)
#pragma unroll
  for (int mt = 0; mt < 4; ++mt)
#pragma unroll
    for (int nt = 0; nt < 4; ++nt) {
      const int n = n0 + wc * 64 + nt * 16 + (lane & 15);
#pragma unroll
      for (int r = 0; r < 4; ++r) {
        const int m = m0 + wr * 64 + mt * 16 + (lane >> 4) * 4 + r;
        sc[(size_t)m * 65536 + n] = f2bf(acc[mt][nt][r]);
      }
    }
}

// ---------------------------------------------------------------------------
// Per-row: 8192-bin histogram threshold on bf16 scores -> candidates
// (margin = 1 bin = 8 bf16 ulps ~ 0.125 at |v| in [2,4)) -> exact fp64
// rescore -> exact top-64 -> write final fp32 row.
// ---------------------------------------------------------------------------
__global__ __launch_bounds__(256) void topk_kernel(const unsigned short* __restrict__ sc,
                                                   const float* __restrict__ x,
                                                   const float* __restrict__ w,
                                                   const double* __restrict__ invd,
                                                   float* __restrict__ out) {
  const int b = blockIdx.x, t = threadIdx.x;
  const unsigned short* srow = sc + (size_t)b * 65536;

  __shared__ unsigned int hist[HWORDS];   // 8192 u16 bins, 2 per word
  __shared__ __align__(16) float xs[D_ACT];
  __shared__ int    cidx[MAXC];
  __shared__ double cval[MAXC];
  __shared__ unsigned int csum[256];
  __shared__ int   selidx[K_SPARSE];
  __shared__ float selval[K_SPARSE];
  __shared__ unsigned int ccnt, scnt;
  __shared__ int binT;

  for (int i = t; i < HWORDS; i += 256) hist[i] = 0;
  const float4* x4 = (const float4*)(x + (size_t)b * D_ACT);
  ((float4*)xs)[t] = x4[t];
  ((float4*)xs)[t + 256] = x4[t + 256];
  if (t == 0) { ccnt = 0; scnt = 0; }
  __syncthreads();

  // pass 1: 13-bit-key histogram (bin = key>>3, packed u16)
  for (int i = t; i < N_FEAT / 8; i += 256) {
    us8 v = ((const us8*)srow)[i];
#pragma unroll
    for (int j = 0; j < 8; ++j) {
      unsigned bin = bfkey((unsigned)v[j]) >> 3;
      atomicAdd(&hist[bin >> 1], 1u << ((bin & 1u) * 16u));
    }
  }
  __syncthreads();

  // per-thread chunk sums (32 bins = 16 words each)
  unsigned cs = 0;
#pragma unroll
  for (int i = 0; i < 16; ++i) { unsigned wv = hist[t * 16 + i]; cs += (wv & 0xFFFFu) + (wv >> 16); }
  csum[t] = cs;
  __syncthreads();

  if (t == 0) {
    unsigned cum = 0; int c = 255;
    for (; c > 0; --c) { if (cum + csum[c] >= (unsigned)K_SPARSE) break; cum += csum[c]; }
    int bb = c * 32 + 31;
    for (;; --bb) {
      unsigned cnt = (hist[bb >> 1] >> ((bb & 1) * 16)) & 0xFFFFu;
      cum += cnt;
      if (cum >= (unsigned)K_SPARSE) break;
    }
    binT = bb;
  }
  __syncthreads();

  // pass 2: collect candidates (bins >= binT - MB_BINS)
  const unsigned kthr = (unsigned)max(binT - MB_BINS, 0) << 3;
  for (int i = t; i < N_FEAT / 8; i += 256) {
    us8 v = ((const us8*)srow)[i];
#pragma unroll
    for (int j = 0; j < 8; ++j) {
      unsigned k = bfkey((unsigned)v[j]);
      if (k >= kthr) {
        unsigned p = atomicAdd(&ccnt, 1u);
        if (p < MAXC) cidx[p] = i * 8 + j;
      }
    }
  }
  __syncthreads();

  // pass 3: exact fp64 rescore, one wave per candidate
  const int C = (ccnt < (unsigned)MAXC) ? (int)ccnt : MAXC;
  const int lane = t & 63, wq = t >> 6;
  for (int ci = wq; ci < C; ci += 4) {
    const int idx = cidx[ci];
    const float4* wr4 = (const float4*)(w + (size_t)idx * D_ACT);
    double s = 0.0;
#pragma unroll
    for (int g = 0; g < 8; ++g) {
      float4 v = wr4[g * 64 + lane];
      const float* xp = xs + g * 256 + lane * 4;
      s += (double)v.x * xp[0] + (double)v.y * xp[1] + (double)v.z * xp[2] + (double)v.w * xp[3];
    }
#pragma unroll
    for (int off = 32; off >= 1; off >>= 1) s += __shfl_xor(s, off);
    if (lane == 0) cval[ci] = s * invd[idx];
  }
  __syncthreads();

  // pass 4: exact top-64 among candidates (value desc, index asc)
  for (int i = t; i < C; i += 256) {
    const double vi = cval[i]; const int ii = cidx[i];
    int rank = 0;
    for (int j = 0; j < C; ++j) {
      const double vj = cval[j];
      rank += (vj > vi) || (vj == vi && cidx[j] < ii);
    }
    if (rank < K_SPARSE) {
      unsigned p = atomicAdd(&scnt, 1u);
      selidx[p] = ii; selval[p] = (float)fmax(vi, 0.0);
    }
  }
  __syncthreads();

  // pass 5: write final row (zeros + 64 values) over own slot
  float4 z = {0.f, 0.f, 0.f, 0.f};
  float4* orow = (float4*)(out + (size_t)b * N_FEAT);
  for (int i = t; i < N_FEAT / 4; i += 256) orow[i] = z;
  __syncthreads();
  if (t < K_SPARSE) out[(size_t)b * N_FEAT + selidx[t]] = selval[t];
}

// ---------------------------------------------------------------------------
extern "C" void kernel_launch(void* const* d_in, const int* in_sizes, int n_in,
                              void* d_out, int out_size, void* d_ws, size_t ws_size,
                              hipStream_t stream) {
  const float* x = (const float*)d_in[0];
  const float* w = (const float*)d_in[1];
  float* invf = (float*)d_ws;                       // 128 KiB
  double* invd = (double*)((char*)d_ws + 131072);   // 256 KiB
  char* ob = (char*)d_out;
  unsigned short* sc = (unsigned short*)d_out;
  float* out = (float*)d_out;

  norm_kernel<<<dim3(N_FEAT), dim3(256), 0, stream>>>(w, invf, invd);
  cvt_x_kernel<<<dim3(2048), dim3(256), 0, stream>>>(x, ob);
  cvt_w_kernel<<<dim3(2048), dim3(256), 0, stream>>>(w, invf, ob);
  gemm_bf16_kernel<<<dim3(N_FEAT / 128, BATCH / 128), dim3(256), 0, stream>>>(ob, sc);
  topk_kernel<<<dim3(BATCH), dim3(256), 0, stream>>>(sc, x, w, invd, out);
}

// Round 4
// 2763.961 us; speedup vs baseline: 6.5155x; 1.1004x over previous
//
#include <hip/hip_runtime.h>
#include <math.h>

#define D_ACT    2048
#define N_FEAT   32768
#define K_SPARSE 64
#define BATCH    8192

// bf16 operand region lives in the upper 64KB of each 128KB output slot.
// logical operand byte j -> d_out byte 65536 + (j & 65535) + ((j>>16)<<17)
#define XB_BYTES 33554432u   // BATCH*D_ACT*2
#define HWORDS   4096        // 8192 u16 bins packed in 4096 u32 words
#define PRELIM   512
#define MAXB     192
#define MAXA     64

typedef __attribute__((ext_vector_type(8))) short short8;
typedef __attribute__((ext_vector_type(4))) float f32x4;
typedef __attribute__((ext_vector_type(8))) unsigned short us8;

__device__ __forceinline__ unsigned obyte(unsigned j) {
  return 65536u + (j & 65535u) + ((j >> 16) << 17);
}

__device__ __forceinline__ unsigned short f2bf(float f) {
  unsigned u = __float_as_uint(f);
  return (unsigned short)((u + 0x7FFFu + ((u >> 16) & 1u)) >> 16);
}

__device__ __forceinline__ float bf2f(unsigned short h) {
  return __uint_as_float(((unsigned)h) << 16);
}

// bf16 bits -> monotone 16-bit key
__device__ __forceinline__ unsigned bfkey(unsigned h) {
  return (h & 0x8000u) ? (~h & 0xFFFFu) : (h | 0x8000u);
}

// ---------------------------------------------------------------------------
// Fused: inv_norm (fp64) + scale + bf16 convert of W into operand region.
// One block per dictionary row.
// ---------------------------------------------------------------------------
__global__ __launch_bounds__(256) void normcvt_w_kernel(const float* __restrict__ w,
                                                        double* __restrict__ invd,
                                                        char* __restrict__ ob) {
  const int row = blockIdx.x, t = threadIdx.x;
  const float4* w4 = (const float4*)(w + (size_t)row * D_ACT);
  float4 v0 = w4[t];
  float4 v1 = w4[t + 256];
  double s = (double)v0.x * v0.x + (double)v0.y * v0.y + (double)v0.z * v0.z + (double)v0.w * v0.w
           + (double)v1.x * v1.x + (double)v1.y * v1.y + (double)v1.z * v1.z + (double)v1.w * v1.w;
  __shared__ double red[256];
  red[t] = s; __syncthreads();
  for (int off = 128; off > 0; off >>= 1) { if (t < off) red[t] += red[t + off]; __syncthreads(); }
  const double invD = 1.0 / (sqrt(red[0]) + 1e-6);
  if (t == 0) invd[row] = invD;
  const float inv = (float)invD;
  // thread t owns elements [t*8, t*8+8): v0 = elems t*4.., v1 = elems 1024+t*4..
  // -> NOT contiguous 8; write two ushort4 at the matching byte offsets instead.
  ushort4 o0, o1;
  o0.x = f2bf(v0.x * inv); o0.y = f2bf(v0.y * inv); o0.z = f2bf(v0.z * inv); o0.w = f2bf(v0.w * inv);
  o1.x = f2bf(v1.x * inv); o1.y = f2bf(v1.y * inv); o1.z = f2bf(v1.z * inv); o1.w = f2bf(v1.w * inv);
  const unsigned base = XB_BYTES + (unsigned)row * 4096u;
  *(ushort4*)(ob + obyte(base + (unsigned)t * 8u)) = o0;
  *(ushort4*)(ob + obyte(base + 2048u + (unsigned)t * 8u)) = o1;
}

// ---------------------------------------------------------------------------
// fp32 -> bf16 converter for x.
// ---------------------------------------------------------------------------
__global__ __launch_bounds__(256) void cvt_x_kernel(const float* __restrict__ x,
                                                    char* __restrict__ ob) {
  const int NT = BATCH * D_ACT / 4;
  for (int i = blockIdx.x * 256 + threadIdx.x; i < NT; i += gridDim.x * 256) {
    float4 v = ((const float4*)x)[i];
    ushort4 o; o.x = f2bf(v.x); o.y = f2bf(v.y); o.z = f2bf(v.z); o.w = f2bf(v.w);
    *(ushort4*)(ob + obyte((unsigned)i * 8u)) = o;
  }
}

// ---------------------------------------------------------------------------
// bf16 MFMA GEMM (UNCHANGED from R3): scores = xb @ wb^T, 128x128 tile, BK=64.
// ---------------------------------------------------------------------------
__global__ __launch_bounds__(256) void gemm_bf16_kernel(const char* __restrict__ ob,
                                                        unsigned short* __restrict__ sc) {
  __shared__ char As[16384];
  __shared__ char Bs[16384];
  const int t = threadIdx.x;
  const int lane = t & 63, wid = t >> 6;
  const int wr = wid >> 1, wc = wid & 1;
  const int m0 = blockIdx.y * 128, n0 = blockIdx.x * 128;

  f32x4 acc[4][4];
#pragma unroll
  for (int i = 0; i < 4; ++i)
#pragma unroll
    for (int j = 0; j < 4; ++j)
#pragma unroll
      for (int q = 0; q < 4; ++q) acc[i][j][q] = 0.f;

  for (int kt = 0; kt < D_ACT / 64; ++kt) {
    const unsigned kb = (unsigned)kt * 128u;
#pragma unroll
    for (int i = 0; i < 4; ++i) {
      const int idx = i * 256 + t;
      const int row = idx >> 3, ch = idx & 7;
      const int sch = ch ^ (row & 7);
      const unsigned jA = (unsigned)(m0 + row) * 4096u + kb + (unsigned)sch * 16u;
      const unsigned jB = XB_BYTES + (unsigned)(n0 + row) * 4096u + kb + (unsigned)sch * 16u;
      __builtin_amdgcn_global_load_lds(
          (const __attribute__((address_space(1))) unsigned int*)(ob + obyte(jA)),
          (__attribute__((address_space(3))) unsigned int*)(As + idx * 16), 16, 0, 0);
      __builtin_amdgcn_global_load_lds(
          (const __attribute__((address_space(1))) unsigned int*)(ob + obyte(jB)),
          (__attribute__((address_space(3))) unsigned int*)(Bs + idx * 16), 16, 0, 0);
    }
    __syncthreads();
#pragma unroll
    for (int kc = 0; kc < 2; ++kc) {
      short8 a[4], b[4];
#pragma unroll
      for (int mt = 0; mt < 4; ++mt) {
        const int row = wr * 64 + mt * 16 + (lane & 15);
        const int c = kc * 4 + (lane >> 4);
        a[mt] = *(const short8*)(As + row * 128 + (c ^ (row & 7)) * 16);
      }
#pragma unroll
      for (int nt = 0; nt < 4; ++nt) {
        const int row = wc * 64 + nt * 16 + (lane & 15);
        const int c = kc * 4 + (lane >> 4);
        b[nt] = *(const short8*)(Bs + row * 128 + (c ^ (row & 7)) * 16);
      }
#pragma unroll
      for (int mt = 0; mt < 4; ++mt)
#pragma unroll
        for (int nt = 0; nt < 4; ++nt)
          acc[mt][nt] = __builtin_amdgcn_mfma_f32_16x16x32_bf16(a[mt], b[nt], acc[mt][nt], 0, 0, 0);
    }
    __syncthreads();
  }

#pragma unroll
  for (int mt = 0; mt < 4; ++mt)
#pragma unroll
    for (int nt = 0; nt < 4; ++nt) {
      const int n = n0 + wc * 64 + nt * 16 + (lane & 15);
#pragma unroll
      for (int r = 0; r < 4; ++r) {
        const int m = m0 + wr * 64 + mt * 16 + (lane >> 4) * 4 + r;
        sc[(size_t)m * 65536 + n] = f2bf(acc[mt][nt][r]);
      }
    }
}

// ---------------------------------------------------------------------------
// topk v2: single score pass (hist + static-threshold prelim collect) ->
// binT -> A (definite, bf16 values) / B (window, fp64 rescore) -> write.
//   A = bins >= binT+3  (>=1-bin gap above B => provably in top-64)
//   B = bins [binT-1, binT+2]  (resolve boundary exactly)
//   C excluded (>=1-bin gap below the 64 in bins >= binT)
// Gap 1 bin = 8 bf16 ulps >= 0.0625 at the threshold region > 2*E (E~0.014).
// ---------------------------------------------------------------------------
__global__ __launch_bounds__(256) void topk_kernel(const unsigned short* __restrict__ sc,
                                                   const float* __restrict__ x,
                                                   const float* __restrict__ w,
                                                   const double* __restrict__ invd,
                                                   float* __restrict__ out) {
  const int b = blockIdx.x, t = threadIdx.x;
  const unsigned short* srow = sc + (size_t)b * 65536;

  __shared__ unsigned int hist[HWORDS];   // 8192 u16 bins, 2 per word
  __shared__ unsigned short pIdx[PRELIM], pBits[PRELIM];
  __shared__ unsigned int csum[256];
  __shared__ unsigned short aIdx[MAXA], aBits[MAXA];
  __shared__ unsigned short bIdx[MAXB];
  __shared__ double bVal[MAXB];
  __shared__ int   selIdx[MAXA];
  __shared__ float selVal[MAXA];
  __shared__ unsigned int pc, ac, bc, snt;
  __shared__ int binT;

  for (int i = t; i < HWORDS; i += 256) hist[i] = 0;
  if (t == 0) { pc = 0; ac = 0; bc = 0; snt = 0; }
  __syncthreads();

  const unsigned SKEY = bfkey((unsigned)f2bf(2.375f));

  // pass 1: histogram + static-threshold prelim collection (single read)
  for (int i = t; i < N_FEAT / 8; i += 256) {
    us8 v = ((const us8*)srow)[i];
#pragma unroll
    for (int j = 0; j < 8; ++j) {
      unsigned bits = (unsigned)v[j];
      unsigned k = bfkey(bits);
      unsigned bin = k >> 3;
      atomicAdd(&hist[bin >> 1], 1u << ((bin & 1u) * 16u));
      if (k >= SKEY) {
        unsigned p = atomicAdd(&pc, 1u);
        if (p < PRELIM) { pIdx[p] = (unsigned short)(i * 8 + j); pBits[p] = (unsigned short)bits; }
      }
    }
  }
  __syncthreads();

  // binT scan
  unsigned cs = 0;
#pragma unroll
  for (int i = 0; i < 16; ++i) { unsigned wv = hist[t * 16 + i]; cs += (wv & 0xFFFFu) + (wv >> 16); }
  csum[t] = cs;
  __syncthreads();
  if (t == 0) {
    unsigned cum = 0; int c = 255;
    for (; c > 0; --c) { if (cum + csum[c] >= (unsigned)K_SPARSE) break; cum += csum[c]; }
    int bb = c * 32 + 31;
    for (;; --bb) {
      unsigned cnt = (hist[bb >> 1] >> ((bb & 1) * 16)) & 0xFFFFu;
      cum += cnt;
      if (cum >= (unsigned)K_SPARSE) break;
    }
    binT = bb;
  }
  __syncthreads();

  const unsigned kA = (unsigned)(binT + 3) << 3;
  const unsigned kB = (unsigned)(binT - 1) << 3;

  // fallback (never taken statistically; exact-safety backstop): prelim
  // overflow or static threshold above window floor -> exact re-collect.
  if (pc > (unsigned)PRELIM || kB < SKEY) {
    if (t == 0) pc = 0;
    __syncthreads();
    for (int i = t; i < N_FEAT / 8; i += 256) {
      us8 v = ((const us8*)srow)[i];
#pragma unroll
      for (int j = 0; j < 8; ++j) {
        unsigned bits = (unsigned)v[j];
        unsigned k = bfkey(bits);
        if (k >= kB) {
          unsigned p = atomicAdd(&pc, 1u);
          if (p < PRELIM) { pIdx[p] = (unsigned short)(i * 8 + j); pBits[p] = (unsigned short)bits; }
        }
      }
    }
    __syncthreads();
  }

  // filter prelim -> A / B
  const int P = (pc < (unsigned)PRELIM) ? (int)pc : PRELIM;
  for (int i = t; i < P; i += 256) {
    unsigned k = bfkey((unsigned)pBits[i]);
    if (k >= kA) {
      unsigned p = atomicAdd(&ac, 1u);
      if (p < (unsigned)MAXA) { aIdx[p] = pIdx[i]; aBits[p] = pBits[i]; }
    } else if (k >= kB) {
      unsigned p = atomicAdd(&bc, 1u);
      if (p < (unsigned)MAXB) bIdx[p] = pIdx[i];
    }
  }
  __syncthreads();

  const int A = (ac < (unsigned)MAXA) ? (int)ac : MAXA;
  const int B = (bc < (unsigned)MAXB) ? (int)bc : MAXB;
  const int need = K_SPARSE - A;   // >= 1 since A <= |bins >= binT+1| <= 63

  // rescore B: one wave per candidate, fp64, x/W read from global (L1/L2-hot)
  const int lane = t & 63, wq = t >> 6;
  const float4* xr4 = (const float4*)(x + (size_t)b * D_ACT);
  for (int ci = wq; ci < B; ci += 4) {
    const int idx = bIdx[ci];
    const float4* wr4 = (const float4*)(w + (size_t)idx * D_ACT);
    double s = 0.0;
#pragma unroll
    for (int g = 0; g < 8; ++g) {
      float4 wv = wr4[g * 64 + lane];
      float4 xv = xr4[g * 64 + lane];
      s += (double)wv.x * xv.x + (double)wv.y * xv.y + (double)wv.z * xv.z + (double)wv.w * xv.w;
    }
#pragma unroll
    for (int off = 32; off >= 1; off >>= 1) s += __shfl_xor(s, off);
    if (lane == 0) bVal[ci] = s * invd[idx];
  }
  __syncthreads();

  // rank B (value desc, index asc), select top-need
  for (int i = t; i < B; i += 256) {
    const double vi = bVal[i]; const int ii = bIdx[i];
    int r = 0;
    for (int j = 0; j < B; ++j) {
      const double vj = bVal[j];
      r += (vj > vi) || (vj == vi && bIdx[j] < ii);
    }
    if (r < need) {
      unsigned p = atomicAdd(&snt, 1u);
      selIdx[p] = ii; selVal[p] = (float)fmax(bVal[i], 0.0);
    }
  }
  __syncthreads();

  // write row: zeros, then scatter A (bf16 values) + selected B (exact values)
  float4 z = {0.f, 0.f, 0.f, 0.f};
  float* orowf = out + (size_t)b * N_FEAT;
  float4* orow = (float4*)orowf;
  for (int i = t; i < N_FEAT / 4; i += 256) orow[i] = z;
  __syncthreads();
  if (t < A) orowf[aIdx[t]] = fmaxf(bf2f(aBits[t]), 0.f);
  const int S = (int)snt;
  if (t >= 64 && t - 64 < S) orowf[selIdx[t - 64]] = selVal[t - 64];
}

// ---------------------------------------------------------------------------
extern "C" void kernel_launch(void* const* d_in, const int* in_sizes, int n_in,
                              void* d_out, int out_size, void* d_ws, size_t ws_size,
                              hipStream_t stream) {
  const float* x = (const float*)d_in[0];
  const float* w = (const float*)d_in[1];
  double* invd = (double*)d_ws;             // 256 KiB
  char* ob = (char*)d_out;
  unsigned short* sc = (unsigned short*)d_out;
  float* out = (float*)d_out;

  normcvt_w_kernel<<<dim3(N_FEAT), dim3(256), 0, stream>>>(w, invd, ob);
  cvt_x_kernel<<<dim3(2048), dim3(256), 0, stream>>>(x, ob);
  gemm_bf16_kernel<<<dim3(N_FEAT / 128, BATCH / 128), dim3(256), 0, stream>>>(ob, sc);
  topk_kernel<<<dim3(BATCH), dim3(256), 0, stream>>>(sc, x, w, invd, out);
}